// Round 3
// baseline (682.588 us; speedup 1.0000x reference)
//
#include <hip/hip_runtime.h>

#define B_ 2
#define S_ 2048
#define D_ 768
#define P_ 16
#define SCALE 0.03608439182435161f  // 768^-0.5

typedef __bf16 bf16x8 __attribute__((ext_vector_type(8)));
typedef float floatx4 __attribute__((ext_vector_type(4)));
using u16 = unsigned short;

__device__ __forceinline__ u16 f2bf(float f) {
    union { float f; unsigned u; } v; v.f = f;
    return (u16)((v.u + 0x7fffu + ((v.u >> 16) & 1u)) >> 16);
}
__device__ __forceinline__ bf16x8 load8(const u16* p) {
    return *reinterpret_cast<const bf16x8*>(p);
}

// ---- normalize patch indices: int64 (little-endian: [v,0,v,0,...]) or int32 ----
// raw32[1]==0 iff int64 (if int32, raw[1]=2nd index >= 1, strictly increasing from >=0).
__global__ void norm_idx(const int* __restrict__ raw, int* __restrict__ nidx) {
    bool is64 = (raw[1] == 0);
    int t = threadIdx.x;
    if (t < B_ * P_) nidx[t] = is64 ? raw[2 * t] : raw[t];
}

// ---- convert x (fp32) -> bf16, 8 elements/thread ----
__global__ __launch_bounds__(256) void convert_x(const float* __restrict__ x,
                                                 u16* __restrict__ xb) {
    int i = (blockIdx.x * 256 + threadIdx.x) * 8;
    const float4* p = reinterpret_cast<const float4*>(x + i);
    float4 a = p[0], b = p[1];
    u16 o[8] = {f2bf(a.x), f2bf(a.y), f2bf(a.z), f2bf(a.w),
                f2bf(b.x), f2bf(b.y), f2bf(b.z), f2bf(b.w)};
    *reinterpret_cast<ulonglong2*>(xb + i) = *reinterpret_cast<ulonglong2*>(o);
}

// ---- convert+transpose weights: WT[z][n][k] = bf16(W[z][k][n]) ----
__global__ void transpose_w(const float* __restrict__ Wq, const float* __restrict__ Wk,
                            const float* __restrict__ Wv, u16* __restrict__ WT) {
    __shared__ float tile[32][33];
    int z = blockIdx.z;
    const float* W = z == 0 ? Wq : (z == 1 ? Wk : Wv);
    u16* T = WT + (size_t)z * D_ * D_;
    int x0 = blockIdx.x * 32, y0 = blockIdx.y * 32;
    int tx = threadIdx.x, ty = threadIdx.y;
#pragma unroll
    for (int j = 0; j < 32; j += 8)
        tile[ty + j][tx] = W[(size_t)(y0 + ty + j) * D_ + x0 + tx];
    __syncthreads();
#pragma unroll
    for (int j = 0; j < 32; j += 8)
        T[(size_t)(x0 + ty + j) * D_ + y0 + tx] = f2bf(tile[tx][ty + j]);
}

// ---- QKV projection: y = x @ W + b ; z=0->q, z=1->k, z=2->v (stored transposed) ----
__global__ __launch_bounds__(256) void qkv_gemm(
    const u16* __restrict__ xb, const u16* __restrict__ WT,
    const float* __restrict__ bq, const float* __restrict__ bk, const float* __restrict__ bv,
    u16* __restrict__ qws, u16* __restrict__ kws, u16* __restrict__ vtws) {
    int z = blockIdx.z;
    const u16* Wt = WT + (size_t)z * D_ * D_;
    const float* bias = z == 0 ? bq : (z == 1 ? bk : bv);
    int wave = threadIdx.x >> 6, lane = threadIdx.x & 63;
    int quad = lane >> 4, l16 = lane & 15;
    int m0 = blockIdx.x * 64 + wave * 16;   // 64 rows per block, 16 per wave
    int n0 = blockIdx.y * 64;

    floatx4 acc[4];
#pragma unroll
    for (int t = 0; t < 4; ++t) acc[t] = (floatx4)(0.0f);

    for (int k = 0; k < D_; k += 32) {
        bf16x8 a = load8(xb + (size_t)(m0 + l16) * D_ + k + quad * 8);
#pragma unroll
        for (int t = 0; t < 4; ++t) {
            bf16x8 bfr = load8(Wt + (size_t)(n0 + t * 16 + l16) * D_ + k + quad * 8);
            acc[t] = __builtin_amdgcn_mfma_f32_16x16x32_bf16(a, bfr, acc[t], 0, 0, 0);
        }
    }
#pragma unroll
    for (int t = 0; t < 4; ++t) {
        int n = n0 + t * 16 + l16;
        float bsv = bias[n];
#pragma unroll
        for (int r = 0; r < 4; ++r) {
            int m = m0 + quad * 4 + r;   // C layout: col = lane&15, row = quad*4+reg
            u16 h = f2bf(acc[t][r] + bsv);
            if (z == 0) {
                qws[(size_t)m * D_ + n] = h;
            } else if (z == 1) {
                kws[(size_t)m * D_ + n] = h;
            } else {
                int bb = m >> 11, s = m & (S_ - 1);
                vtws[((size_t)bb * D_ + n) * S_ + s] = h;   // vT[b][d][s]
            }
        }
    }
}

// ---- per-patch flash attention: out[b,p,q,:] = softmax(q·k_seg^T * scale) @ v_seg ----
__global__ __launch_bounds__(256) void attn_kernel(
    const int* __restrict__ idx, const u16* __restrict__ qws,
    const u16* __restrict__ kws, const u16* __restrict__ vtws,
    float* __restrict__ out) {
    int b = blockIdx.z, p = blockIdx.y, q0 = blockIdx.x * 16;
    int start = idx[b * P_ + p];
    int end = (p == P_ - 1) ? S_ : idx[b * P_ + p + 1];
    int s32 = start & ~31;
    int e32 = (end + 31) & ~31;          // <= S_ since S_ % 32 == 0
    int nch = (e32 - s32 + 127) >> 7;    // 128-key chunks; every chunk has >=1 valid key

    int tid = threadIdx.x;
    int wave = tid >> 6, lane = tid & 63, quad = lane >> 4, l16 = lane & 15;

    __shared__ __align__(16) u16 Plds[16][136];
    __shared__ float smax[4][16], ssum[4][16], m_sh[16], l_sh[16], alpha_sh[16];
    if (tid < 16) { m_sh[tid] = -1e30f; l_sh[tid] = 0.f; }
    __syncthreads();

    floatx4 O[12];
#pragma unroll
    for (int t = 0; t < 12; ++t) O[t] = (floatx4)(0.0f);

    const u16* Qb = qws + (size_t)(b * S_ + q0) * D_;
    const u16* Kb = kws + (size_t)b * S_ * D_;
    const u16* Vb = vtws + (size_t)b * D_ * S_;

    for (int c = 0; c < nch; ++c) {
        int kb = s32 + c * 128;
        int key_base = kb + wave * 32;

        // ---- stage a: scores for this wave's 32 keys (2 x 16) over K=768 ----
        floatx4 sc[2];
        sc[0] = (floatx4)(0.0f); sc[1] = (floatx4)(0.0f);
        for (int kd = 0; kd < D_; kd += 32) {
            bf16x8 a = load8(Qb + (size_t)l16 * D_ + kd + quad * 8);
#pragma unroll
            for (int t = 0; t < 2; ++t) {
                int key = key_base + t * 16 + l16;
                int keyc = key < S_ ? key : S_ - 1;   // clamp loads, mask later
                bf16x8 bfr = load8(Kb + (size_t)keyc * D_ + kd + quad * 8);
                sc[t] = __builtin_amdgcn_mfma_f32_16x16x32_bf16(a, bfr, sc[t], 0, 0, 0);
            }
        }
        // scale + mask + per-row max (row quad*4+r; cols over l16 within quad)
        float rm[4];
#pragma unroll
        for (int r = 0; r < 4; ++r) rm[r] = -1e30f;
#pragma unroll
        for (int t = 0; t < 2; ++t) {
            int key = key_base + t * 16 + l16;
            bool valid = (key >= start) && (key < end);
#pragma unroll
            for (int r = 0; r < 4; ++r) {
                float s = sc[t][r] * SCALE;
                s = valid ? s : -1e30f;
                sc[t][r] = s;
                rm[r] = fmaxf(rm[r], s);
            }
        }
#pragma unroll
        for (int off = 1; off < 16; off <<= 1) {
#pragma unroll
            for (int r = 0; r < 4; ++r) rm[r] = fmaxf(rm[r], __shfl_xor(rm[r], off));
        }
        if (l16 == 0) {
#pragma unroll
            for (int r = 0; r < 4; ++r) smax[wave][quad * 4 + r] = rm[r];
        }
        __syncthreads();

        // ---- stage b: combine maxima, compute alpha ----
        if (tid < 16) {
            float nm = m_sh[tid];
#pragma unroll
            for (int w = 0; w < 4; ++w) nm = fmaxf(nm, smax[w][tid]);
            alpha_sh[tid] = expf(m_sh[tid] - nm);
            m_sh[tid] = nm;
        }
        __syncthreads();

        // ---- stage c: P -> LDS (bf16), row sums, rescale O ----
        float nmv[4], al[4];
#pragma unroll
        for (int r = 0; r < 4; ++r) { nmv[r] = m_sh[quad * 4 + r]; al[r] = alpha_sh[quad * 4 + r]; }
        float rs[4] = {0.f, 0.f, 0.f, 0.f};
#pragma unroll
        for (int t = 0; t < 2; ++t) {
            int key = key_base + t * 16 + l16;
            bool valid = (key >= start) && (key < end);
#pragma unroll
            for (int r = 0; r < 4; ++r) {
                float pv = valid ? expf(sc[t][r] - nmv[r]) : 0.f;
                Plds[quad * 4 + r][wave * 32 + t * 16 + l16] = f2bf(pv);
                rs[r] += pv;
            }
        }
#pragma unroll
        for (int off = 1; off < 16; off <<= 1) {
#pragma unroll
            for (int r = 0; r < 4; ++r) rs[r] += __shfl_xor(rs[r], off);
        }
        if (l16 == 0) {
#pragma unroll
            for (int r = 0; r < 4; ++r) ssum[wave][quad * 4 + r] = rs[r];
        }
#pragma unroll
        for (int t = 0; t < 12; ++t) {
#pragma unroll
            for (int r = 0; r < 4; ++r) O[t][r] *= al[r];
        }
        __syncthreads();

        // ---- stage d: l update (16 threads) + PV for this wave's 192 dims ----
        if (tid < 16)
            l_sh[tid] = l_sh[tid] * alpha_sh[tid]
                      + ssum[0][tid] + ssum[1][tid] + ssum[2][tid] + ssum[3][tid];

        bf16x8 ap[4];
#pragma unroll
        for (int ks = 0; ks < 4; ++ks)
            ap[ks] = load8(&Plds[l16][ks * 32 + quad * 8]);   // A[m=lane&15][k=quad*8+j]
#pragma unroll
        for (int t = 0; t < 12; ++t) {
            int dcol = wave * 192 + t * 16 + l16;
            const u16* vrow = Vb + (size_t)dcol * S_;
#pragma unroll
            for (int ks = 0; ks < 4; ++ks) {
                int koff = kb + ks * 32 + quad * 8;
                int ksafe = (koff + 8 <= S_) ? koff : (S_ - 8);  // P=0 for clamped keys
                bf16x8 bfr = load8(vrow + ksafe);
                O[t] = __builtin_amdgcn_mfma_f32_16x16x32_bf16(ap[ks], bfr, O[t], 0, 0, 0);
            }
        }
    }
    __syncthreads();   // l_sh final before read

    float inv[4];
#pragma unroll
    for (int r = 0; r < 4; ++r) inv[r] = 1.f / fmaxf(l_sh[quad * 4 + r], 1e-20f);
    size_t obase = (((size_t)(b * P_ + p) * S_) + q0) * D_;
#pragma unroll
    for (int t = 0; t < 12; ++t) {
        int dcol = wave * 192 + t * 16 + l16;
#pragma unroll
        for (int r = 0; r < 4; ++r)
            out[obase + (size_t)(quad * 4 + r) * D_ + dcol] = O[t][r] * inv[r];
    }
}

extern "C" void kernel_launch(void* const* d_in, const int* in_sizes, int n_in,
                              void* d_out, int out_size, void* d_ws, size_t ws_size,
                              hipStream_t stream) {
    const float* x  = (const float*)d_in[0];
    const int* idxraw = (const int*)d_in[1];
    const float* Wq = (const float*)d_in[2];
    const float* bq = (const float*)d_in[3];
    const float* Wk = (const float*)d_in[4];
    const float* bk = (const float*)d_in[5];
    const float* Wv = (const float*)d_in[6];
    const float* bv = (const float*)d_in[7];
    float* out = (float*)d_out;

    u16* ws = (u16*)d_ws;
    const size_t SD = (size_t)B_ * S_ * D_;          // 3,145,728 elements
    u16* xb   = ws;                                  // bf16 x
    u16* qws  = xb + SD;
    u16* kws  = qws + SD;
    u16* vtws = kws + SD;
    u16* wtws = vtws + SD;                           // 3 * 768 * 768 bf16
    int* nidx = (int*)(wtws + (size_t)3 * D_ * D_);  // 32 ints

    norm_idx<<<1, 64, 0, stream>>>(idxraw, nidx);
    convert_x<<<dim3(SD / (256 * 8)), dim3(256), 0, stream>>>(x, xb);
    transpose_w<<<dim3(24, 24, 3), dim3(32, 8), 0, stream>>>(Wq, Wk, Wv, wtws);
    qkv_gemm<<<dim3(64, 12, 3), dim3(256), 0, stream>>>(xb, wtws, bq, bk, bv, qws, kws, vtws);
    attn_kernel<<<dim3(128, 16, 2), dim3(256), 0, stream>>>(nidx, qws, kws, vtws, out);
}

// Round 4
// 679.162 us; speedup vs baseline: 1.0050x; 1.0050x over previous
//
#include <hip/hip_runtime.h>

#define B_ 2
#define S_ 2048
#define D_ 768
#define P_ 16
// 768^-0.5 * log2(e): scores kept in log2 domain so exp -> native v_exp_f32
#define SCALE_LOG2 0.0520587723834f

typedef __bf16 bf16x8 __attribute__((ext_vector_type(8)));
typedef float floatx4 __attribute__((ext_vector_type(4)));
using u16 = unsigned short;

__device__ __forceinline__ u16 f2bf(float f) {
    union { float f; unsigned u; } v; v.f = f;
    return (u16)((v.u + 0x7fffu + ((v.u >> 16) & 1u)) >> 16);
}
__device__ __forceinline__ bf16x8 load8(const u16* p) {
    return *reinterpret_cast<const bf16x8*>(p);
}

// ---- normalize patch indices: int64 (little-endian [v,0,...]) or int32 ----
__global__ void norm_idx(const int* __restrict__ raw, int* __restrict__ nidx) {
    bool is64 = (raw[1] == 0);
    int t = threadIdx.x;
    if (t < B_ * P_) nidx[t] = is64 ? raw[2 * t] : raw[t];
}

// ---- convert x (fp32) -> bf16, 8 elements/thread ----
__global__ __launch_bounds__(256) void convert_x(const float* __restrict__ x,
                                                 u16* __restrict__ xb) {
    int i = (blockIdx.x * 256 + threadIdx.x) * 8;
    const float4* p = reinterpret_cast<const float4*>(x + i);
    float4 a = p[0], b = p[1];
    u16 o[8] = {f2bf(a.x), f2bf(a.y), f2bf(a.z), f2bf(a.w),
                f2bf(b.x), f2bf(b.y), f2bf(b.z), f2bf(b.w)};
    *reinterpret_cast<ulonglong2*>(xb + i) = *reinterpret_cast<ulonglong2*>(o);
}

// ---- convert+transpose weights: WT[z][n][k] = bf16(W[z][k][n]) ----
__global__ void transpose_w(const float* __restrict__ Wq, const float* __restrict__ Wk,
                            const float* __restrict__ Wv, u16* __restrict__ WT) {
    __shared__ float tile[32][33];
    int z = blockIdx.z;
    const float* W = z == 0 ? Wq : (z == 1 ? Wk : Wv);
    u16* T = WT + (size_t)z * D_ * D_;
    int x0 = blockIdx.x * 32, y0 = blockIdx.y * 32;
    int tx = threadIdx.x, ty = threadIdx.y;
#pragma unroll
    for (int j = 0; j < 32; j += 8)
        tile[ty + j][tx] = W[(size_t)(y0 + ty + j) * D_ + x0 + tx];
    __syncthreads();
#pragma unroll
    for (int j = 0; j < 32; j += 8)
        T[(size_t)(x0 + ty + j) * D_ + y0 + tx] = f2bf(tile[tx][ty + j]);
}

// ---- fused QKV projection over N=2304 (Q|K|V); per-wave 32x64 tile ----
__global__ __launch_bounds__(256) void qkv_gemm(
    const u16* __restrict__ xb, const u16* __restrict__ WT,
    const float* __restrict__ bq, const float* __restrict__ bk, const float* __restrict__ bv,
    u16* __restrict__ qws, u16* __restrict__ kws, u16* __restrict__ vtws) {
    int ng0 = blockIdx.y * 64;          // global n in [0, 2304)
    int z = ng0 / 768;                  // 0->q, 1->k, 2->v
    int n0 = ng0 - z * 768;
    const u16* Wt = WT + (size_t)z * D_ * D_;
    const float* bias = z == 0 ? bq : (z == 1 ? bk : bv);
    int wave = threadIdx.x >> 6, lane = threadIdx.x & 63;
    int quad = lane >> 4, l16 = lane & 15;
    int m0 = blockIdx.x * 128 + wave * 32;

    floatx4 acc[2][4];
#pragma unroll
    for (int i = 0; i < 2; ++i)
#pragma unroll
        for (int t = 0; t < 4; ++t) acc[i][t] = (floatx4)(0.0f);

    const u16* xr0 = xb + (size_t)(m0 + l16) * D_;
    const u16* xr1 = xb + (size_t)(m0 + 16 + l16) * D_;
    const u16* wr = Wt + (size_t)(n0 + l16) * D_;
    for (int k = 0; k < D_; k += 32) {
        bf16x8 a0 = load8(xr0 + k + quad * 8);
        bf16x8 a1 = load8(xr1 + k + quad * 8);
#pragma unroll
        for (int t = 0; t < 4; ++t) {
            bf16x8 bfr = load8(wr + (size_t)t * 16 * D_ + k + quad * 8);
            acc[0][t] = __builtin_amdgcn_mfma_f32_16x16x32_bf16(a0, bfr, acc[0][t], 0, 0, 0);
            acc[1][t] = __builtin_amdgcn_mfma_f32_16x16x32_bf16(a1, bfr, acc[1][t], 0, 0, 0);
        }
    }
#pragma unroll
    for (int i = 0; i < 2; ++i) {
#pragma unroll
        for (int t = 0; t < 4; ++t) {
            int n = n0 + t * 16 + l16;
            float bsv = bias[n];
#pragma unroll
            for (int r = 0; r < 4; ++r) {
                int m = m0 + i * 16 + quad * 4 + r;   // C layout: col=lane&15, row=quad*4+r
                u16 h = f2bf(acc[i][t][r] + bsv);
                if (z == 0) {
                    qws[(size_t)m * D_ + n] = h;
                } else if (z == 1) {
                    kws[(size_t)m * D_ + n] = h;
                } else {
                    int bb = m >> 11, s = m & (S_ - 1);
                    vtws[((size_t)bb * D_ + n) * S_ + s] = h;   // vT[b][d][s]
                }
            }
        }
    }
}

// ---- per-patch flash attention, 256-key chunks, 2 barriers/chunk ----
__global__ __launch_bounds__(256) void attn_kernel(
    const int* __restrict__ idx, const u16* __restrict__ qws,
    const u16* __restrict__ kws, const u16* __restrict__ vtws,
    float* __restrict__ out) {
    int b = blockIdx.z, p = blockIdx.y, q0 = blockIdx.x * 16;
    int start = idx[b * P_ + p];
    int end = (p == P_ - 1) ? S_ : idx[b * P_ + p + 1];
    int s32 = start & ~31;
    int e32 = (end + 31) & ~31;          // <= S_ (S_ % 32 == 0)
    int nch = (e32 - s32 + 255) >> 8;

    int tid = threadIdx.x;
    int wave = tid >> 6, lane = tid & 63, quad = lane >> 4, l16 = lane & 15;
    int row = quad * 4;                   // this quad's 4 C-rows

    __shared__ __align__(16) u16 Plds[16][264];   // stride 264: b128 reads 2-way (free)
    __shared__ float smax[4][16], ssum[4][16];

    float m_r[4] = {-3e38f, -3e38f, -3e38f, -3e38f};
    float l_r[4] = {0.f, 0.f, 0.f, 0.f};

    floatx4 O[12];
#pragma unroll
    for (int t = 0; t < 12; ++t) O[t] = (floatx4)(0.0f);

    const u16* Qb = qws + (size_t)(b * S_ + q0) * D_;
    const u16* Kb = kws + (size_t)b * S_ * D_;
    const u16* Vb = vtws + (size_t)b * D_ * S_;

    for (int c = 0; c < nch; ++c) {
        int kb = s32 + c * 256;
        int rem = e32 - kb; if (rem > 256) rem = 256;   // multiple of 32
        int ng32 = rem >> 5;                            // valid 32-key groups

        // ---- QKT: wave's 64 keys (4 tiles), kd-outer (A loaded once/kd) ----
        floatx4 sc[4];
#pragma unroll
        for (int t = 0; t < 4; ++t) sc[t] = (floatx4)(0.0f);
        int ktb[4];
#pragma unroll
        for (int t = 0; t < 4; ++t) {
            int kt = kb + (wave * 4 + t) * 16;
            ktb[t] = kt < e32 - 16 ? kt : e32 - 16;     // clamp loads; mask later
        }
        for (int kd = 0; kd < D_; kd += 32) {
            bf16x8 a = load8(Qb + (size_t)l16 * D_ + kd + quad * 8);
#pragma unroll
            for (int t = 0; t < 4; ++t) {
                bf16x8 bk_ = load8(Kb + (size_t)(ktb[t] + l16) * D_ + kd + quad * 8);
                sc[t] = __builtin_amdgcn_mfma_f32_16x16x32_bf16(a, bk_, sc[t], 0, 0, 0);
            }
        }

        // ---- scale (log2 domain) + mask + per-row max ----
        float rm[4] = {-3e38f, -3e38f, -3e38f, -3e38f};
#pragma unroll
        for (int t = 0; t < 4; ++t) {
            int key = kb + (wave * 4 + t) * 16 + l16;
            bool valid = (key >= start) && (key < end);
#pragma unroll
            for (int r = 0; r < 4; ++r) {
                float s = valid ? sc[t][r] * SCALE_LOG2 : -3e38f;
                sc[t][r] = s;
                rm[r] = fmaxf(rm[r], s);
            }
        }
#pragma unroll
        for (int off = 1; off < 16; off <<= 1) {
#pragma unroll
            for (int r = 0; r < 4; ++r) rm[r] = fmaxf(rm[r], __shfl_xor(rm[r], off));
        }
        if (l16 == 0) {
#pragma unroll
            for (int r = 0; r < 4; ++r) smax[wave][row + r] = rm[r];
        }
        __syncthreads();

        // ---- all lanes: new max + alpha (redundant, no serial stage) ----
        float nm[4], al[4];
#pragma unroll
        for (int r = 0; r < 4; ++r) {
            float v = m_r[r];
#pragma unroll
            for (int w = 0; w < 4; ++w) v = fmaxf(v, smax[w][row + r]);
            nm[r] = v;
            al[r] = exp2f(m_r[r] - v);
            m_r[r] = v;
        }

        // ---- P (bf16) -> LDS + row sums; rescale O ----
        float rs[4] = {0.f, 0.f, 0.f, 0.f};
#pragma unroll
        for (int t = 0; t < 4; ++t) {
#pragma unroll
            for (int r = 0; r < 4; ++r) {
                float pv = exp2f(sc[t][r] - nm[r]);   // masked -> exp2(-huge) = 0
                Plds[row + r][wave * 64 + t * 16 + l16] = f2bf(pv);
                rs[r] += pv;
            }
        }
#pragma unroll
        for (int off = 1; off < 16; off <<= 1) {
#pragma unroll
            for (int r = 0; r < 4; ++r) rs[r] += __shfl_xor(rs[r], off);
        }
        if (l16 == 0) {
#pragma unroll
            for (int r = 0; r < 4; ++r) ssum[wave][row + r] = rs[r];
        }
#pragma unroll
        for (int t = 0; t < 12; ++t) {
#pragma unroll
            for (int r = 0; r < 4; ++r) O[t][r] *= al[r];
        }
        __syncthreads();

        // ---- l update (redundant per-quad) + PV over valid 32-key groups ----
#pragma unroll
        for (int r = 0; r < 4; ++r)
            l_r[r] = l_r[r] * al[r]
                   + ssum[0][row + r] + ssum[1][row + r] + ssum[2][row + r] + ssum[3][row + r];

        for (int g = 0; g < ng32; ++g) {
            bf16x8 ap = load8(&Plds[l16][g * 32 + quad * 8]);
            const u16* vcol = Vb + kb + g * 32 + quad * 8;
#pragma unroll
            for (int t = 0; t < 12; ++t) {
                int dcol = wave * 192 + t * 16 + l16;
                bf16x8 bv_ = load8(vcol + (size_t)dcol * S_);
                O[t] = __builtin_amdgcn_mfma_f32_16x16x32_bf16(ap, bv_, O[t], 0, 0, 0);
            }
        }
    }

    float inv[4];
#pragma unroll
    for (int r = 0; r < 4; ++r) inv[r] = 1.f / fmaxf(l_r[r], 1e-30f);
    size_t obase = (((size_t)(b * P_ + p) * S_) + q0) * D_;
#pragma unroll
    for (int t = 0; t < 12; ++t) {
        int dcol = wave * 192 + t * 16 + l16;
#pragma unroll
        for (int r = 0; r < 4; ++r)
            out[obase + (size_t)(row + r) * D_ + dcol] = O[t][r] * inv[r];
    }
}

extern "C" void kernel_launch(void* const* d_in, const int* in_sizes, int n_in,
                              void* d_out, int out_size, void* d_ws, size_t ws_size,
                              hipStream_t stream) {
    const float* x  = (const float*)d_in[0];
    const int* idxraw = (const int*)d_in[1];
    const float* Wq = (const float*)d_in[2];
    const float* bq = (const float*)d_in[3];
    const float* Wk = (const float*)d_in[4];
    const float* bk = (const float*)d_in[5];
    const float* Wv = (const float*)d_in[6];
    const float* bv = (const float*)d_in[7];
    float* out = (float*)d_out;

    u16* ws = (u16*)d_ws;
    const size_t SD = (size_t)B_ * S_ * D_;          // 3,145,728 elements
    u16* xb   = ws;
    u16* qws  = xb + SD;
    u16* kws  = qws + SD;
    u16* vtws = kws + SD;
    u16* wtws = vtws + SD;                           // 3 * 768 * 768 bf16
    int* nidx = (int*)(wtws + (size_t)3 * D_ * D_);

    norm_idx<<<1, 64, 0, stream>>>(idxraw, nidx);
    convert_x<<<dim3(SD / (256 * 8)), dim3(256), 0, stream>>>(x, xb);
    transpose_w<<<dim3(24, 24, 3), dim3(32, 8), 0, stream>>>(Wq, Wk, Wv, wtws);
    qkv_gemm<<<dim3(32, 36), dim3(256), 0, stream>>>(xb, wtws, bq, bk, bv, qws, kws, vtws);
    attn_kernel<<<dim3(128, 16, 2), dim3(256), 0, stream>>>(nidx, qws, kws, vtws, out);
}